// Round 5
// baseline (28.286 us; speedup 1.0000x reference)
//
#include <hip/hip_runtime.h>

// FSNeuronDecoupled: per-element spiking scan over T=8 steps.
//   v0 = x;  for t in 0..7:  s_t = (v - theta_t > 0);  v -= h_t * s_t
//   y = sum_t d_t * s_t
// with theta_t = theta[grain(t)]^-(t+1), etc.  GRAIN = [0,0,0,0,1,1,1,1].
// Memory-bound streaming op: 4B read + 4B write per element, zero reuse.
// R4: persistent waves with 4-deep batched loads (max memory-level
//     parallelism per wave, m13-copy-probe style). Exact-divide fast path:
//     2048 blocks x 256 thr x 8 vec = n4, no bounds checks.

#define T_STEPS 8
#define BATCH 4

typedef float f32x4 __attribute__((ext_vector_type(4)));

struct Coef {
    float th[T_STEPS], hh[T_STEPS], dd[T_STEPS];
};

__device__ __forceinline__ void make_coef(
    const float* __restrict__ d, const float* __restrict__ h,
    const float* __restrict__ theta, Coef& c)
{
    // theta_t = theta[g]^-(t+1) * TAU (TAU==1). Running reciprocal products:
    // exact powers of two for the provided inputs, matching np bit-for-bit.
    const float it0 = 1.0f / theta[0], it1 = 1.0f / theta[1];
    const float ih0 = 1.0f / h[0],     ih1 = 1.0f / h[1];
    const float id0 = 1.0f / d[0],     id1 = 1.0f / d[1];
    float pt0 = 1.0f, pt1 = 1.0f, ph0 = 1.0f, ph1 = 1.0f, pd0 = 1.0f, pd1 = 1.0f;
#pragma unroll
    for (int t = 0; t < T_STEPS; ++t) {
        pt0 *= it0; pt1 *= it1;
        ph0 *= ih0; ph1 *= ih1;
        pd0 *= id0; pd1 *= id1;
        const bool g1 = (t >= 4);           // GRAIN = [0,0,0,0,1,1,1,1]
        c.th[t] = g1 ? pt1 : pt0;
        c.hh[t] = g1 ? ph1 : ph0;
        c.dd[t] = g1 ? pd1 : pd0;
    }
}

__device__ __forceinline__ f32x4 fs_step(const f32x4 v_in, const Coef& c) {
    f32x4 v = v_in;
    f32x4 acc = {0.0f, 0.0f, 0.0f, 0.0f};
#pragma unroll
    for (int t = 0; t < T_STEPS; ++t) {
#pragma unroll
        for (int e = 0; e < 4; ++e) {
            const float s = (v[e] > c.th[t]) ? 1.0f : 0.0f;
            v[e]   -= c.hh[t] * s;
            acc[e] += c.dd[t] * s;
        }
    }
    return acc;
}

__global__ __launch_bounds__(256) void fsneuron_kernel(
    const f32x4* __restrict__ x4,
    const float* __restrict__ d,
    const float* __restrict__ h,
    const float* __restrict__ theta,
    f32x4* __restrict__ y4,
    int n4,
    int exact)   // 1: n4 == nthreads*2*BATCH, skip all bounds checks
{
    Coef c;
    make_coef(d, h, theta, c);

    const int tid    = blockIdx.x * blockDim.x + threadIdx.x;
    const int stride = gridDim.x * blockDim.x;

    if (exact) {
        // two 4-deep batches, zero branches
        int base = tid;
#pragma unroll
        for (int rep = 0; rep < 2; ++rep) {
            f32x4 v[BATCH];
#pragma unroll
            for (int b = 0; b < BATCH; ++b)
                v[b] = __builtin_nontemporal_load(&x4[base + b * stride]);
#pragma unroll
            for (int b = 0; b < BATCH; ++b)
                v[b] = fs_step(v[b], c);
#pragma unroll
            for (int b = 0; b < BATCH; ++b)
                __builtin_nontemporal_store(v[b], &y4[base + b * stride]);
            base += BATCH * stride;
        }
        return;
    }

    // general path: 4-deep batches while they fit, then single-vector tail
    int i = tid;
    for (; i + (BATCH - 1) * stride < n4; i += BATCH * stride) {
        f32x4 v[BATCH];
#pragma unroll
        for (int b = 0; b < BATCH; ++b)
            v[b] = __builtin_nontemporal_load(&x4[i + b * stride]);
#pragma unroll
        for (int b = 0; b < BATCH; ++b)
            v[b] = fs_step(v[b], c);
#pragma unroll
        for (int b = 0; b < BATCH; ++b)
            __builtin_nontemporal_store(v[b], &y4[i + b * stride]);
    }
    for (; i < n4; i += stride) {
        const f32x4 r = fs_step(__builtin_nontemporal_load(&x4[i]), c);
        __builtin_nontemporal_store(r, &y4[i]);
    }
}

// Scalar remainder (n % 4 != 0) — dead for this problem size but kept correct.
__global__ __launch_bounds__(64) void fsneuron_tail_kernel(
    const float* __restrict__ x,
    const float* __restrict__ d,
    const float* __restrict__ h,
    const float* __restrict__ theta,
    float* __restrict__ y,
    int start, int n_total)
{
    const int i = start + blockIdx.x * blockDim.x + threadIdx.x;
    if (i >= n_total) return;

    Coef c;
    make_coef(d, h, theta, c);

    float v = x[i];
    float acc = 0.0f;
#pragma unroll
    for (int t = 0; t < T_STEPS; ++t) {
        const float s = (v > c.th[t]) ? 1.0f : 0.0f;
        v   -= c.hh[t] * s;
        acc += c.dd[t] * s;
    }
    y[i] = acc;
}

extern "C" void kernel_launch(void* const* d_in, const int* in_sizes, int n_in,
                              void* d_out, int out_size, void* d_ws, size_t ws_size,
                              hipStream_t stream) {
    const float* x     = (const float*)d_in[0];
    const float* d     = (const float*)d_in[1];
    const float* h     = (const float*)d_in[2];
    const float* theta = (const float*)d_in[3];
    float* y = (float*)d_out;

    const int n  = in_sizes[0];   // B*N*1 = 16,777,216
    const int n4 = n / 4;         // 4,194,304

    const int block = 256;
    int grid = 2048;              // 256 CU x 8 blocks/CU
    const long long per_sweep = (long long)grid * block * 2 * BATCH;
    const int exact = (per_sweep == (long long)n4) ? 1 : 0;
    if (!exact) {
        grid = (n4 + block - 1) / block;
        if (grid > 2048) grid = 2048;
        if (grid < 1) grid = 1;
    }

    fsneuron_kernel<<<grid, block, 0, stream>>>(
        (const f32x4*)x, d, h, theta, (f32x4*)y, n4, exact);

    const int tail = n - n4 * 4;
    if (tail > 0) {
        fsneuron_tail_kernel<<<(tail + 63) / 64, 64, 0, stream>>>(
            x, d, h, theta, y, n4 * 4, n);
    }
}

// Round 6
// 26.913 us; speedup vs baseline: 1.0510x; 1.0510x over previous
//
#include <hip/hip_runtime.h>

// FSNeuronDecoupled: per-element spiking scan over T=8 steps.
//   v0 = x;  for t in 0..7:  s_t = (v - theta_t > 0);  v -= h_t * s_t
//   y = sum_t d_t * s_t
// with theta_t = theta[grain(t)]^-(t+1), etc.  GRAIN = [0,0,0,0,1,1,1,1].
// Memory-bound streaming op: 4B read + 4B write per element, zero reuse.
// R5: fillBuffer-style shape — LOW occupancy (512 blocks = 2/CU), each block
//     streams a CONTIGUOUS 128 KB region with 8-deep batches (DRAM row
//     locality, less channel thrash). Exact-divide fast path, nt stores.

#define T_STEPS 8
#define BATCH 8
#define VPT 32            // float4s per thread on the exact path (4 reps x 8)

typedef float f32x4 __attribute__((ext_vector_type(4)));

struct Coef {
    float th[T_STEPS], hh[T_STEPS], dd[T_STEPS];
};

__device__ __forceinline__ void make_coef(
    const float* __restrict__ d, const float* __restrict__ h,
    const float* __restrict__ theta, Coef& c)
{
    // theta_t = theta[g]^-(t+1) * TAU (TAU==1). Running reciprocal products:
    // exact powers of two for the provided inputs, matching np bit-for-bit.
    const float it0 = 1.0f / theta[0], it1 = 1.0f / theta[1];
    const float ih0 = 1.0f / h[0],     ih1 = 1.0f / h[1];
    const float id0 = 1.0f / d[0],     id1 = 1.0f / d[1];
    float pt0 = 1.0f, pt1 = 1.0f, ph0 = 1.0f, ph1 = 1.0f, pd0 = 1.0f, pd1 = 1.0f;
#pragma unroll
    for (int t = 0; t < T_STEPS; ++t) {
        pt0 *= it0; pt1 *= it1;
        ph0 *= ih0; ph1 *= ih1;
        pd0 *= id0; pd1 *= id1;
        const bool g1 = (t >= 4);           // GRAIN = [0,0,0,0,1,1,1,1]
        c.th[t] = g1 ? pt1 : pt0;
        c.hh[t] = g1 ? ph1 : ph0;
        c.dd[t] = g1 ? pd1 : pd0;
    }
}

__device__ __forceinline__ f32x4 fs_step(const f32x4 v_in, const Coef& c) {
    f32x4 v = v_in;
    f32x4 acc = {0.0f, 0.0f, 0.0f, 0.0f};
#pragma unroll
    for (int t = 0; t < T_STEPS; ++t) {
#pragma unroll
        for (int e = 0; e < 4; ++e) {
            const float s = (v[e] > c.th[t]) ? 1.0f : 0.0f;
            v[e]   -= c.hh[t] * s;
            acc[e] += c.dd[t] * s;
        }
    }
    return acc;
}

__global__ __launch_bounds__(256) void fsneuron_kernel(
    const f32x4* __restrict__ x4,
    const float* __restrict__ d,
    const float* __restrict__ h,
    const float* __restrict__ theta,
    f32x4* __restrict__ y4,
    int n4,
    int exact)   // 1: n4 == gridDim.x * 256 * VPT — block-contiguous, no bounds checks
{
    Coef c;
    make_coef(d, h, theta, c);

    if (exact) {
        // Each block owns a contiguous region of 256*VPT float4s (128 KB).
        // Wave reads 1 KB/instr; 8 loads in flight before any dependent use.
        int idx = blockIdx.x * (256 * VPT) + threadIdx.x;
#pragma unroll
        for (int rep = 0; rep < VPT / BATCH; ++rep) {
            f32x4 v[BATCH];
#pragma unroll
            for (int b = 0; b < BATCH; ++b)
                v[b] = x4[idx + b * 256];
#pragma unroll
            for (int b = 0; b < BATCH; ++b)
                v[b] = fs_step(v[b], c);
#pragma unroll
            for (int b = 0; b < BATCH; ++b)
                __builtin_nontemporal_store(v[b], &y4[idx + b * 256]);
            idx += BATCH * 256;
        }
        return;
    }

    // general fallback: grid-stride with 4-deep batches, then single tail
    const int tid    = blockIdx.x * blockDim.x + threadIdx.x;
    const int stride = gridDim.x * blockDim.x;
    int i = tid;
    for (; i + 3 * stride < n4; i += 4 * stride) {
        f32x4 v[4];
#pragma unroll
        for (int b = 0; b < 4; ++b) v[b] = x4[i + b * stride];
#pragma unroll
        for (int b = 0; b < 4; ++b) v[b] = fs_step(v[b], c);
#pragma unroll
        for (int b = 0; b < 4; ++b)
            __builtin_nontemporal_store(v[b], &y4[i + b * stride]);
    }
    for (; i < n4; i += stride) {
        const f32x4 r = fs_step(x4[i], c);
        __builtin_nontemporal_store(r, &y4[i]);
    }
}

// Scalar remainder (n % 4 != 0) — dead for this problem size but kept correct.
__global__ __launch_bounds__(64) void fsneuron_tail_kernel(
    const float* __restrict__ x,
    const float* __restrict__ d,
    const float* __restrict__ h,
    const float* __restrict__ theta,
    float* __restrict__ y,
    int start, int n_total)
{
    const int i = start + blockIdx.x * blockDim.x + threadIdx.x;
    if (i >= n_total) return;

    Coef c;
    make_coef(d, h, theta, c);

    float v = x[i];
    float acc = 0.0f;
#pragma unroll
    for (int t = 0; t < T_STEPS; ++t) {
        const float s = (v > c.th[t]) ? 1.0f : 0.0f;
        v   -= c.hh[t] * s;
        acc += c.dd[t] * s;
    }
    y[i] = acc;
}

extern "C" void kernel_launch(void* const* d_in, const int* in_sizes, int n_in,
                              void* d_out, int out_size, void* d_ws, size_t ws_size,
                              hipStream_t stream) {
    const float* x     = (const float*)d_in[0];
    const float* d     = (const float*)d_in[1];
    const float* h     = (const float*)d_in[2];
    const float* theta = (const float*)d_in[3];
    float* y = (float*)d_out;

    const int n  = in_sizes[0];   // B*N*1 = 16,777,216
    const int n4 = n / 4;         // 4,194,304

    const int block = 256;
    int grid = 512;               // 2 blocks/CU — low occupancy, deep streams
    int exact = ((long long)grid * block * VPT == (long long)n4) ? 1 : 0;
    if (!exact) {
        grid = (n4 + block - 1) / block;
        if (grid > 2048) grid = 2048;
        if (grid < 1) grid = 1;
    }

    fsneuron_kernel<<<grid, block, 0, stream>>>(
        (const f32x4*)x, d, h, theta, (f32x4*)y, n4, exact);

    const int tail = n - n4 * 4;
    if (tail > 0) {
        fsneuron_tail_kernel<<<(tail + 63) / 64, 64, 0, stream>>>(
            x, d, h, theta, y, n4 * 4, n);
    }
}